// Round 3
// baseline (101.437 us; speedup 1.0000x reference)
//
#include <hip/hip_runtime.h>
#include <hip/hip_bf16.h>
#include <math.h>

#define TPB 256   // 4 waves per block; each wave owns a 32-row block
#define JCH 8     // j-chunks (grid.y): 128 x 8 = 1024 blocks = 4 wg/CU

#if defined(__has_builtin)
#  if __has_builtin(__builtin_amdgcn_exp2f)
#    define EXP2F(x) __builtin_amdgcn_exp2f(x)
#  else
#    define EXP2F(x) exp2f(x)
#  endif
#else
#  define EXP2F(x) exp2f(x)
#endif

typedef __attribute__((ext_vector_type(8))) short short8v;   // 8 bf16 (4 VGPRs)
typedef __attribute__((ext_vector_type(16))) float f32x16;   // 32x32 acc

// Normalize velocities, pre-scale by sqrt(log2(e)), convert to bf16x4 (x,y,z,0)
// so mfma dot(w_i, u_j) = s_ij * log2(e). Zero per-row accumulators and out.
__global__ __launch_bounds__(TPB) void prep_kernel(const float* __restrict__ v,
                                                   ushort4* __restrict__ U,
                                                   float* __restrict__ Zacc,
                                                   float* __restrict__ Sacc,
                                                   float* __restrict__ out, int N) {
    int i = blockIdx.x * TPB + threadIdx.x;
    if (i == 0) out[0] = 0.0f;
    if (i < N) {
        float x = v[3 * i + 0], y = v[3 * i + 1], z = v[3 * i + 2];
        float n = sqrtf(x * x + y * y + z * z) + 1e-6f;
        float s = 1.2011224087864498f / n;  // sqrt(log2(e)) / (|v| + 1e-6)
        __hip_bfloat16 bx = __float2bfloat16(x * s);
        __hip_bfloat16 by = __float2bfloat16(y * s);
        __hip_bfloat16 bz = __float2bfloat16(z * s);
        ushort4 u;
        u.x = *(unsigned short*)&bx;
        u.y = *(unsigned short*)&by;
        u.z = *(unsigned short*)&bz;
        u.w = 0;
        U[i] = u;
        Zacc[i] = 0.0f;
        Sacc[i] = 0.0f;
    }
}

// Each wave: 32-row block x one j-chunk. Dots via mfma_f32_32x32x16_bf16
// (K=3 zero-padded to 16; data at elems 0..2 of lanes 0..31 in BOTH A and B,
// so any HW k-permutation applies identically to both operands).
// C/D layout: col = lane&31, row = (reg&3) + 8*(reg>>2) + 4*(lane>>5).
__global__ __launch_bounds__(TPB) void pair_kernel(const ushort4* __restrict__ U,
                                                   float* __restrict__ Zacc,
                                                   float* __restrict__ Sacc, int N) {
    int tid = threadIdx.x;
    int lane = tid & 63;
    int wave = tid >> 6;
    int half = lane >> 5;
    int lid = lane & 31;

    int rbase = blockIdx.x * (4 * 32) + wave * 32;
    int chunk_len = N / JCH;        // 2048
    int jbase = blockIdx.y * chunk_len;
    int ntiles = chunk_len / 32;    // 64

    // A fragment: rows of this wave's block (lanes 0..31; zeros in upper half)
    ushort4 aw = U[rbase + lid];
    short8v afrag = (short8v)0;
    if (half == 0) {
        afrag[0] = (short)aw.x;
        afrag[1] = (short)aw.y;
        afrag[2] = (short)aw.z;
    }

    float Zp[16], Sp[16];
#pragma unroll
    for (int r = 0; r < 16; ++r) { Zp[r] = 0.0f; Sp[r] = 0.0f; }

    const f32x16 czero = (f32x16)0.0f;

    ushort4 bw = U[jbase + lid];  // prefetch tile 0
    for (int t = 0; t < ntiles; ++t) {
        ushort4 bw_next = bw;
        if (t + 1 < ntiles) bw_next = U[jbase + (t + 1) * 32 + lid];

        short8v bfrag = (short8v)0;
        if (half == 0) {
            bfrag[0] = (short)bw.x;
            bfrag[1] = (short)bw.y;
            bfrag[2] = (short)bw.z;
        }
        f32x16 acc = __builtin_amdgcn_mfma_f32_32x32x16_bf16(afrag, bfrag, czero, 0, 0, 0);

#pragma unroll
        for (int r = 0; r < 16; ++r) {
            float tt = acc[r];
            float e = EXP2F(tt);      // exp2(t) = exp(s)
            Zp[r] += e;
            Sp[r] = fmaf(tt, e, Sp[r]);
        }
        bw = bw_next;
    }

    // Reduce across the 32 lanes sharing each row set (xor masks stay in-half),
    // then one atomicAdd per row per array.
#pragma unroll
    for (int r = 0; r < 16; ++r) {
        float z = Zp[r], s = Sp[r];
#pragma unroll
        for (int m = 1; m <= 16; m <<= 1) {
            z += __shfl_xor(z, m);
            s += __shfl_xor(s, m);
        }
        if (lid == 0) {
            int row = rbase + (r & 3) + 8 * (r >> 2) + 4 * half;
            atomicAdd(&Zacc[row], z);
            atomicAdd(&Sacc[row], s);
        }
    }
}

// Per-row entropy, then mean-reduce into out[0].
__global__ __launch_bounds__(TPB) void final_kernel(const float* __restrict__ Zacc,
                                                    const float* __restrict__ Sacc,
                                                    float* __restrict__ out, int N) {
    int row = blockIdx.x * TPB + threadIdx.x;
    float contrib = 0.0f;
    if (row < N) {
        float Z = Zacc[row];
        float S = Sacc[row];
        const float LN2 = 0.6931471805599453f;
        // H = ln Z - S_nat/Z - eps*N ;  S_nat = ln2 * S' ;  ln Z = ln2 * log2 Z
        float H = LN2 * (log2f(Z) - S / Z) - 1e-8f * (float)N;
        contrib = H / (float)N;
    }
    for (int off = 32; off > 0; off >>= 1)
        contrib += __shfl_down(contrib, off);
    __shared__ float red[TPB / 64];
    int lane = threadIdx.x & 63;
    int wv = threadIdx.x >> 6;
    if (lane == 0) red[wv] = contrib;
    __syncthreads();
    if (threadIdx.x == 0) {
        float s = 0.f;
        for (int w = 0; w < TPB / 64; ++w) s += red[w];
        atomicAdd(out, s);
    }
}

extern "C" void kernel_launch(void* const* d_in, const int* in_sizes, int n_in,
                              void* d_out, int out_size, void* d_ws, size_t ws_size,
                              hipStream_t stream) {
    const float* vel = (const float*)d_in[0];
    // d_in[1] (positions) is unused by the reference math.
    int N = in_sizes[0] / 3;
    float* out = (float*)d_out;

    char* ws = (char*)d_ws;
    ushort4* U = (ushort4*)ws;                                  // N * 8 B
    float* Zacc = (float*)(ws + (size_t)N * sizeof(ushort4));   // N floats
    float* Sacc = Zacc + N;                                     // N floats

    int nb = (N + TPB - 1) / TPB;
    prep_kernel<<<nb, TPB, 0, stream>>>(vel, U, Zacc, Sacc, out, N);
    dim3 grid(N / 128, JCH);
    pair_kernel<<<grid, TPB, 0, stream>>>(U, Zacc, Sacc, N);
    final_kernel<<<nb, TPB, 0, stream>>>(Zacc, Sacc, out, N);
}

// Round 5
// 92.875 us; speedup vs baseline: 1.0922x; 1.0922x over previous
//
#include <hip/hip_runtime.h>
#include <hip/hip_bf16.h>
#include <math.h>

#define TPB 256    // 4 waves per block; each wave owns a 32-row block
#define JCH 12     // j-chunks: grid = 128 x 12 = 1536 blocks = exactly 6 wg/CU
#define MAXCH 1376 // max chunk rows (43 tiles of 32); last chunk = 1248 (39 tiles)

#if defined(__has_builtin)
#  if __has_builtin(__builtin_amdgcn_exp2f)
#    define EXP2F(x) __builtin_amdgcn_exp2f(x)
#  else
#    define EXP2F(x) exp2f(x)
#  endif
#else
#  define EXP2F(x) exp2f(x)
#endif

typedef __attribute__((ext_vector_type(8))) short short8v;   // 8 bf16 (4 VGPRs)
typedef __attribute__((ext_vector_type(16))) float f32x16;   // 32x32 acc

__device__ __forceinline__ unsigned short f2bf(float f) {
    __hip_bfloat16 b = __float2bfloat16(f);
    return *(unsigned short*)&b;
}

// One kernel does it all except the final row->scalar reduce.
// Each wave: 32-row block x one j-chunk. Dot via mfma_f32_32x32x16_bf16
// (K=3 zero-padded; vectors pre-scaled by sqrt(log2 e) so t = s*log2(e)).
// C/D layout: col = lane&31, row = (reg&3) + 8*(reg>>2) + 4*(lane>>5).
__global__ __launch_bounds__(TPB, 6) void pair_kernel(const float* __restrict__ vel,
                                                      float* __restrict__ partZ,
                                                      float* __restrict__ partS, int N) {
    __shared__ __align__(16) unsigned int smem[(MAXCH * 16 + 16) / 4];
    int tid = threadIdx.x;
    int lane = tid & 63, wave = tid >> 6, half = lane >> 5, lid = lane & 31;
    int chunk = blockIdx.y;
    int jbase = chunk * MAXCH;
    int len = N - jbase; if (len > MAXCH) len = MAXCH;

    // Stage normalized, log2e-prescaled bf16 chunk rows into LDS (16B/row: x,y,z,0...).
    for (int j = tid; j < len; j += TPB) {
        int g = jbase + j;
        float x = vel[3 * g], y = vel[3 * g + 1], z = vel[3 * g + 2];
        float n = sqrtf(fmaf(x, x, fmaf(y, y, z * z))) + 1e-6f;
        float s = 1.2011224087864498f / n;  // sqrt(log2 e) / (|v| + 1e-6)
        uint4 w;
        w.x = (unsigned)f2bf(x * s) | ((unsigned)f2bf(y * s) << 16);
        w.y = (unsigned)f2bf(z * s);
        w.z = 0u; w.w = 0u;
        ((uint4*)smem)[j] = w;
    }
    if (tid == 0) ((uint4*)smem)[MAXCH] = make_uint4(0u, 0u, 0u, 0u);  // zero slot

    // A fragment: this wave's 32 rows in lanes 0..31; upper half & k>=3 are zero.
    int rbase = blockIdx.x * 128 + wave * 32;
    short8v afrag = (short8v)0;
    if (half == 0) {
        int g = rbase + lid;
        float x = vel[3 * g], y = vel[3 * g + 1], z = vel[3 * g + 2];
        float n = sqrtf(fmaf(x, x, fmaf(y, y, z * z))) + 1e-6f;
        float s = 1.2011224087864498f / n;
        afrag[0] = (short)f2bf(x * s);
        afrag[1] = (short)f2bf(y * s);
        afrag[2] = (short)f2bf(z * s);
    }
    __syncthreads();

    int ntiles = len >> 5;
    const char* lds = (const char*)smem;
    int vaddr = half ? (MAXCH * 16) : (lid * 16);  // upper half -> fixed zero slot
    int vinc = half ? 0 : 512;

    float Zp[16], Sp[16];
#pragma unroll
    for (int r = 0; r < 16; ++r) { Zp[r] = 0.0f; Sp[r] = 0.0f; }
    const f32x16 czero = (f32x16)0.0f;

    for (int t = 0; t < ntiles; ++t) {
        short8v bfrag = *(const short8v*)(lds + vaddr);  // ds_read_b128
        vaddr += vinc;
        f32x16 acc = __builtin_amdgcn_mfma_f32_32x32x16_bf16(afrag, bfrag, czero, 0, 0, 0);
#pragma unroll
        for (int r = 0; r < 16; ++r) {
            float tt = acc[r];
            float e = EXP2F(tt);  // exp2(t) = exp(s)
            Zp[r] += e;
            Sp[r] = fmaf(tt, e, Sp[r]);
        }
    }

    // Reduce across the 32 lanes of each half (same row set), store partials.
#pragma unroll
    for (int r = 0; r < 16; ++r) {
        float z = Zp[r], s = Sp[r];
#pragma unroll
        for (int m = 1; m <= 16; m <<= 1) {
            z += __shfl_xor(z, m);
            s += __shfl_xor(s, m);
        }
        if (lid == 0) {
            int row = rbase + (r & 3) + 8 * (r >> 2) + 4 * half;
            partZ[(size_t)chunk * N + row] = z;
            partS[(size_t)chunk * N + row] = s;
        }
    }
}

// Per-row entropy from chunk partials, then mean-reduce into out[0].
__global__ __launch_bounds__(TPB) void final_kernel(const float* __restrict__ partZ,
                                                    const float* __restrict__ partS,
                                                    float* __restrict__ out, int N) {
    int row = blockIdx.x * TPB + threadIdx.x;
    float contrib = 0.0f;
    if (row < N) {
        float Z = 0.f, S = 0.f;
        for (int c = 0; c < JCH; ++c) {
            Z += partZ[(size_t)c * N + row];
            S += partS[(size_t)c * N + row];
        }
        const float LN2 = 0.6931471805599453f;
        // H = ln Z - S_nat/Z - eps*N ;  S_nat = ln2 * S' ;  ln Z = ln2 * log2 Z
        float H = LN2 * (log2f(Z) - S / Z) - 1e-8f * (float)N;
        contrib = H / (float)N;
    }
    for (int off = 32; off; off >>= 1) contrib += __shfl_down(contrib, off);
    __shared__ float red[TPB / 64];
    if ((threadIdx.x & 63) == 0) red[threadIdx.x >> 6] = contrib;
    __syncthreads();
    if (threadIdx.x == 0) {
        float s = 0.f;
        for (int w = 0; w < TPB / 64; ++w) s += red[w];
        atomicAdd(out, s);
    }
}

extern "C" void kernel_launch(void* const* d_in, const int* in_sizes, int n_in,
                              void* d_out, int out_size, void* d_ws, size_t ws_size,
                              hipStream_t stream) {
    const float* vel = (const float*)d_in[0];
    // d_in[1] (positions) is unused by the reference math.
    int N = in_sizes[0] / 3;
    float* out = (float*)d_out;

    float* partZ = (float*)d_ws;                 // JCH * N floats (pure stores)
    float* partS = partZ + (size_t)JCH * N;      // JCH * N floats

    hipMemsetAsync(d_out, 0, sizeof(float), stream);
    dim3 grid(N / 128, JCH);
    pair_kernel<<<grid, TPB, 0, stream>>>(vel, partZ, partS, N);
    final_kernel<<<(N + TPB - 1) / TPB, TPB, 0, stream>>>(partZ, partS, out, N);
}